// Round 11
// baseline (212.436 us; speedup 1.0000x reference)
//
#include <hip/hip_runtime.h>

#define N 8192
#define LOGN 13
#define IN_DIM 128
#define HID 64
#define NC 2
#define MLPW 64
#define NWORDS (N * (size_t)N / 32)   // 2,097,152 bitmask words
#define CAP 256                       // per-row compact capacity (avg deg ~79, ~20 sigma margin)

typedef unsigned int uint;
typedef float f4 __attribute__((ext_vector_type(4)));

// ---------------- kernel 1: fire-and-forget bitmask build ----------------
__global__ void dedup_or_kernel(const int* __restrict__ idx, int E,
                                uint* __restrict__ bitmask)
{
    int e = blockIdx.x * blockDim.x + threadIdx.x;
    if (e >= E) return;
    uint g = (uint)idx[e];
    atomicOr(&bitmask[g >> 5], 1u << (g & 31));
}

// per-edge MLP with adj-feature folded into bias; returns softmax[:,1]
__device__ __forceinline__ float edge_mlp(float f1, float f2, float bias_l,
                                          const float* swx, const float* swy,
                                          const float* sb, const float* sw2)
{
    float dl = bias_l;
#pragma unroll 8
    for (int j = 0; j < MLPW; j++) {
        float h = fmaxf(f1 * swx[j] + f2 * swy[j] + sb[j], 0.0f);
        dl += h * sw2[j];
    }
    return 1.0f / (1.0f + expf(dl));
}

// ---------------- kernel 2 (B): gather+MLP at full occupancy ----------------
// Wave per row, ~1 KB LDS -> 32 waves/CU. Each lane owns 4 bitmask words
// (~1.2 edges): all 650k xdeg/ydeg gathers are in flight machine-wide.
// Emits compact (col,p) pairs + rowcnt + drow + col_cnt. No adj_mask touch.
__global__ __launch_bounds__(256) void edgemlp_kernel(
    const uint* __restrict__ bitmask,
    const float* __restrict__ xdeg,
    const float* __restrict__ ydeg,
    const float* __restrict__ Wm1,
    const float* __restrict__ bm1,
    const float* __restrict__ Wm2,
    const float* __restrict__ bm2,
    uint* __restrict__ pairs,
    int* __restrict__ rowcnt,
    float* __restrict__ drow,
    int* __restrict__ col_cnt)
{
    __shared__ float swx[MLPW], swy[MLPW], sb[MLPW], sw2[MLPW];
    __shared__ int wcnt[4];
    int t = threadIdx.x;
    int wid = t >> 6, lane = t & 63;
    if (t < MLPW) {
        swx[t] = Wm1[MLPW + t];                 // weight on xdeg feature
        swy[t] = Wm1[2 * MLPW + t];             // weight on ydeg feature
        sb[t]  = Wm1[t] + bm1[t];               // adj==1.0 folded into bias
        sw2[t] = Wm2[2 * t] - Wm2[2 * t + 1];   // for (l0 - l1)
    }
    if (lane == 0) wcnt[wid] = 0;
    __syncthreads();

    int r = blockIdx.x * 4 + wid;
    size_t rowbase = (size_t)r * N;
    float bias_l = bm2[0] - bm2[1];
    uint4 wv = ((const uint4*)(bitmask + (size_t)r * 256))[lane];
    uint words[4] = {wv.x, wv.y, wv.z, wv.w};
#pragma unroll
    for (int wi = 0; wi < 4; wi++) {
        uint w = words[wi];
        int cb = lane * 128 + wi * 32;          // word (lane*4+wi) covers cols cb..cb+31
        while (w) {
            int b = __ffs(w) - 1;
            w &= w - 1;
            int c = cb + b;
            float p = edge_mlp(xdeg[rowbase + c], ydeg[rowbase + c], bias_l,
                               swx, swy, sb, sw2);
            int k = atomicAdd(&wcnt[wid], 1);
            if (k < CAP) {
                uint q = (uint)fminf(p * 524288.0f, 524287.0f);   // 19-bit fixed point
                pairs[(size_t)r * CAP + k] = ((uint)c << 19) | q;
            }
            atomicAdd(&col_cnt[c], 1);          // fire-and-forget
        }
    }
    __syncthreads();                             // wcnt final
    if (lane == 0) {
        int cnt = wcnt[wid];
        rowcnt[r] = min(cnt, CAP);
        drow[r] = 1.0f / sqrtf((float)(cnt + 1));   // +1 from identity
    }
}

// ---------------- kernel 3: Y[j][d] = dcol[j] * (x[j,:] @ W1[:,d]) ----------------
__global__ __launch_bounds__(256) void xw1_kernel(const float* __restrict__ x,
                                                  const float* __restrict__ W1,
                                                  const int* __restrict__ col_cnt,
                                                  float* __restrict__ Y)
{
    __shared__ float sx[4][IN_DIM];
    int r0 = blockIdx.x * 4;
    for (int t = threadIdx.x; t < 4 * IN_DIM; t += 256)
        sx[t >> 7][t & 127] = x[(size_t)(r0 + (t >> 7)) * IN_DIM + (t & 127)];
    __syncthreads();
    int rr = threadIdx.x >> 6;
    int d = threadIdx.x & 63;
    float acc = 0.0f;
#pragma unroll 8
    for (int k = 0; k < IN_DIM; k++)
        acc += sx[rr][k] * W1[k * HID + d];
    int j = r0 + rr;
    float dc = 1.0f / sqrtf((float)(col_cnt[j] + 1));
    Y[(size_t)j * HID + d] = dc * acc;
}

// ---------------- kernel 4: fused SpMM layer 1 + W2 projection + dcol ----------------
__global__ __launch_bounds__(256) void spmm1_kernel(const float* __restrict__ Y,
                                                    const uint* __restrict__ bitmask,
                                                    const float* __restrict__ drow,
                                                    const int* __restrict__ col_cnt,
                                                    const float* __restrict__ W2,
                                                    float* __restrict__ Zc)
{
    int r = blockIdx.x * 4 + (threadIdx.x >> 6);
    r = __builtin_amdgcn_readfirstlane(r);       // wave-uniform -> SGPR
    int d = threadIdx.x & 63;
    const uint4* wp = (const uint4*)(bitmask + (size_t)r * 256);
    float acc0 = Y[(size_t)r * HID + d];         // identity (+I) term
    float acc1 = 0.0f;
    for (int q = 0; q < 64; q++) {
        uint4 wv = wp[q];                        // wave-uniform scalar load
        uint w0 = wv.x, w1 = wv.y, w2 = wv.z, w3 = wv.w;
        int cb = q * 128;
        while (w0) { int b = __ffs(w0) - 1; w0 &= w0 - 1; acc0 += Y[(size_t)(cb +      b) * HID + d]; }
        while (w1) { int b = __ffs(w1) - 1; w1 &= w1 - 1; acc1 += Y[(size_t)(cb + 32 + b) * HID + d]; }
        while (w2) { int b = __ffs(w2) - 1; w2 &= w2 - 1; acc0 += Y[(size_t)(cb + 64 + b) * HID + d]; }
        while (w3) { int b = __ffs(w3) - 1; w3 &= w3 - 1; acc1 += Y[(size_t)(cb + 96 + b) * HID + d]; }
    }
    float hv = drow[r] * (acc0 + acc1);
    float z0 = hv * W2[d * 2 + 0];
    float z1 = hv * W2[d * 2 + 1];
    for (int off = 32; off >= 1; off >>= 1) {
        z0 += __shfl_xor(z0, off, 64);
        z1 += __shfl_xor(z1, off, 64);
    }
    if (d == 0) {
        float dc = 1.0f / sqrtf((float)(col_cnt[r] + 1));
        Zc[r * 2 + 0] = dc * z0;
        Zc[r * 2 + 1] = dc * z1;
    }
}

// ---------------- kernel 5: SpMM layer 2 off the bitmask ----------------
__global__ __launch_bounds__(256) void spmm2_kernel(const float* __restrict__ Zc,
                                                    const uint* __restrict__ bitmask,
                                                    const float* __restrict__ drow,
                                                    float* __restrict__ out)
{
    int r = blockIdx.x * 4 + (threadIdx.x >> 6);
    r = __builtin_amdgcn_readfirstlane(r);
    int lane = threadIdx.x & 63;
    float a0 = 0.0f, a1 = 0.0f;
#pragma unroll
    for (int i = 0; i < 4; i++) {
        int wi = lane + i * 64;
        uint w = bitmask[(size_t)r * 256 + wi];
        int cb = wi * 32;
        while (w) {
            int b = __ffs(w) - 1;
            w &= w - 1;
            a0 += Zc[(cb + b) * 2 + 0];
            a1 += Zc[(cb + b) * 2 + 1];
        }
    }
    for (int off = 32; off >= 1; off >>= 1) {
        a0 += __shfl_xor(a0, off, 64);
        a1 += __shfl_xor(a1, off, 64);
    }
    if (lane == 0) {
        a0 += Zc[r * 2 + 0];                     // identity (+I) term
        a1 += Zc[r * 2 + 1];
        out[r * 2 + 0] = drow[r] * a0;
        out[r * 2 + 1] = drow[r] * a1;
    }
}

// ---------------- kernel 6 (C): pure-streaming adj_mask writer ----------------
// Zero LDS tile + decode compact pairs + nt-store. No gathers, no MLP.
__global__ __launch_bounds__(512) void stream_kernel(
    const uint* __restrict__ pairs,
    const int* __restrict__ rowcnt,
    float* __restrict__ adj_mask)
{
    __shared__ float sp[256 * 32];          // 32 KB row tile
    int t = threadIdx.x;
    int r = blockIdx.x;
    f4 z4 = {0.f, 0.f, 0.f, 0.f};
#pragma unroll
    for (int i = 0; i < 4; i++) ((f4*)sp)[t + i * 512] = z4;
    __syncthreads();
    int cnt = rowcnt[r];
    if (t < cnt) {
        uint v = pairs[(size_t)r * CAP + t];
        sp[v >> 19] = (float)(v & 0x7FFFF) * (1.0f / 524288.0f);
    }
    __syncthreads();
    f4* dst = (f4*)(adj_mask + (size_t)r * N);
#pragma unroll
    for (int i = 0; i < 4; i++)
        __builtin_nontemporal_store(((f4*)sp)[t + i * 512], dst + t + i * 512);
}

extern "C" void kernel_launch(void* const* d_in, const int* in_sizes, int n_in,
                              void* d_out, int out_size, void* d_ws, size_t ws_size,
                              hipStream_t stream)
{
    const float* x    = (const float*)d_in[0];
    // d_in[1] (adj) unused: adj.flat[idx] == 1.0 by construction
    const float* xdeg = (const float*)d_in[2];
    const float* ydeg = (const float*)d_in[3];
    const float* Wm1  = (const float*)d_in[4];
    const float* bm1  = (const float*)d_in[5];
    const float* Wm2  = (const float*)d_in[6];
    const float* bm2  = (const float*)d_in[7];
    const float* W1   = (const float*)d_in[8];
    const float* W2   = (const float*)d_in[9];
    const int*   idx  = (const int*)d_in[10];
    const int E = in_sizes[10];

    float* out = (float*)d_out;                       // [N*NC]
    float* adj_mask = out + (size_t)N * NC;           // [N*N]

    // ---- workspace carve (~19 MB) ----
    char* ws = (char*)d_ws;
    size_t off = 0;
    auto carve = [&](size_t bytes) -> void* {
        void* p = ws + off;
        off += (bytes + 255) & ~(size_t)255;
        return p;
    };
    uint* bitmask = (uint*)carve(NWORDS * sizeof(uint));
    int* col_cnt  = (int*)carve((size_t)N * sizeof(int));   // adjacent to bitmask
    int* rowcnt   = (int*)carve((size_t)N * sizeof(int));
    float* drow   = (float*)carve((size_t)N * sizeof(float));
    float* Y      = (float*)carve((size_t)N * HID * sizeof(float));
    float* Zc     = (float*)carve((size_t)N * NC * sizeof(float));
    uint* pairs   = (uint*)carve((size_t)N * CAP * sizeof(uint));

    // one memset covers bitmask + col_cnt (contiguous carve)
    hipMemsetAsync(bitmask, 0, NWORDS * sizeof(uint) + (size_t)N * sizeof(int), stream);

    dedup_or_kernel<<<(E + 255) / 256, 256, 0, stream>>>(idx, E, bitmask);
    edgemlp_kernel<<<N / 4, 256, 0, stream>>>(bitmask, xdeg, ydeg, Wm1, bm1, Wm2, bm2,
                                              pairs, rowcnt, drow, col_cnt);
    xw1_kernel<<<N / 4, 256, 0, stream>>>(x, W1, col_cnt, Y);
    spmm1_kernel<<<N / 4, 256, 0, stream>>>(Y, bitmask, drow, col_cnt, W2, Zc);
    spmm2_kernel<<<N / 4, 256, 0, stream>>>(Zc, bitmask, drow, out);
    stream_kernel<<<N, 512, 0, stream>>>(pairs, rowcnt, adj_mask);   // pure stream, last
}

// Round 12
// 150.111 us; speedup vs baseline: 1.4152x; 1.4152x over previous
//
#include <hip/hip_runtime.h>

#define N 8192
#define LOGN 13
#define IN_DIM 128
#define HID 64
#define NC 2
#define MLPW 64
#define NWORDS (N * (size_t)N / 32)   // 2,097,152 bitmask words
#define CAP 768                       // per-row edge list capacity (avg deg ~79)

typedef unsigned int uint;
typedef float f4 __attribute__((ext_vector_type(4)));

// ---------------- kernel 1: fire-and-forget bitmask build ----------------
__global__ void dedup_or_kernel(const int* __restrict__ idx, int E,
                                uint* __restrict__ bitmask)
{
    int e = blockIdx.x * blockDim.x + threadIdx.x;
    if (e >= E) return;
    uint g = (uint)idx[e];
    atomicOr(&bitmask[g >> 5], 1u << (g & 31));
}

// per-edge MLP with adj-feature folded into bias; returns softmax[:,1]
__device__ __forceinline__ float edge_mlp(float f1, float f2, float bias_l,
                                          const float* swx, const float* swy,
                                          const float* sb, const float* sw2)
{
    float dl = bias_l;
#pragma unroll 8
    for (int j = 0; j < MLPW; j++) {
        float h = fmaxf(f1 * swx[j] + f2 * swy[j] + sb[j], 0.0f);
        dl += h * sw2[j];
    }
    return 1.0f / (1.0f + expf(dl));
}

// ---------------- kernel 2: fused zero-fill + compacted edge MLP + degrees ----------------
// One 512-thread block per adjacency ROW. 37 KB LDS -> 4 blocks/CU -> 32 waves/CU.
__global__ __launch_bounds__(512) void mask_kernel(
    const uint* __restrict__ bitmask,
    const float* __restrict__ xdeg,
    const float* __restrict__ ydeg,
    const float* __restrict__ Wm1,
    const float* __restrict__ bm1,
    const float* __restrict__ Wm2,
    const float* __restrict__ bm2,
    float* __restrict__ adj_mask,
    float* __restrict__ drow,
    int* __restrict__ col_cnt)
{
    __shared__ float swx[MLPW], swy[MLPW], sb[MLPW], sw2[MLPW];
    __shared__ float sp[256 * 32];          // 32 KB staging tile (one full row)
    __shared__ int list[CAP];
    __shared__ int cnt;
    __shared__ int spc[8];
    int t = threadIdx.x;
    if (t < MLPW) {
        swx[t] = Wm1[MLPW + t];                 // weight on xdeg feature
        swy[t] = Wm1[2 * MLPW + t];             // weight on ydeg feature
        sb[t]  = Wm1[t] + bm1[t];               // adj==1.0 folded into bias
        sw2[t] = Wm2[2 * t] - Wm2[2 * t + 1];   // for (l0 - l1)
    }
    if (t == 0) cnt = 0;
    int r = blockIdx.x;
    size_t rowbase = (size_t)r * N;
    uint w = (t < 256) ? bitmask[(size_t)r * 256 + t] : 0u;   // load before sync
    f4 z4 = {0.f, 0.f, 0.f, 0.f};
#pragma unroll
    for (int i = 0; i < 4; i++) ((f4*)sp)[t + i * 512] = z4;
    __syncthreads();

    float bias_l = bm2[0] - bm2[1];
    int pc = __popc(w);
    // compact set bits into LDS list (cheap divergent phase: LDS atomics only)
    while (w) {
        int b = __ffs(w) - 1;
        w &= w - 1;
        int c = t * 32 + b;
        int p = atomicAdd(&cnt, 1);
        if (p < CAP) {
            list[p] = c;
        } else {                                // overflow fallback (≈never at avg deg 79)
            sp[c] = edge_mlp(xdeg[rowbase + c], ydeg[rowbase + c], bias_l, swx, swy, sb, sw2);
            atomicAdd(&col_cnt[c], 1);
        }
    }
    __syncthreads();
    int n = min(cnt, CAP);
    // dense MLP phase: one edge per thread, all lanes active
    for (int i = t; i < n; i += 512) {
        int c = list[i];
        sp[c] = edge_mlp(xdeg[rowbase + c], ydeg[rowbase + c], bias_l, swx, swy, sb, sw2);
        atomicAdd(&col_cnt[c], 1);              // fire-and-forget
    }

    // row degree = sum of popcounts (bits are unique by construction)
    for (int off = 32; off >= 1; off >>= 1) pc += __shfl_down(pc, off, 64);
    if ((t & 63) == 0) spc[t >> 6] = pc;
    __syncthreads();                             // also fences sp[] writes
    if (t == 0) {
        int s = 0;
#pragma unroll
        for (int i = 0; i < 8; i++) s += spc[i];
        drow[r] = 1.0f / sqrtf((float)(s + 1));  // +1 from identity
    }

    // stream the finished row out with non-temporal stores
    f4* dst = (f4*)(adj_mask + rowbase);
#pragma unroll
    for (int i = 0; i < 4; i++)
        __builtin_nontemporal_store(((f4*)sp)[t + i * 512], dst + t + i * 512);
}

// ---------------- kernel 3: Y[j][d] = dcol[j] * (x[j,:] @ W1[:,d]) ----------------
__global__ __launch_bounds__(256) void xw1_kernel(const float* __restrict__ x,
                                                  const float* __restrict__ W1,
                                                  const int* __restrict__ col_cnt,
                                                  float* __restrict__ Y)
{
    __shared__ float sx[4][IN_DIM];
    int r0 = blockIdx.x * 4;
    for (int t = threadIdx.x; t < 4 * IN_DIM; t += 256)
        sx[t >> 7][t & 127] = x[(size_t)(r0 + (t >> 7)) * IN_DIM + (t & 127)];
    __syncthreads();
    int rr = threadIdx.x >> 6;
    int d = threadIdx.x & 63;
    float acc = 0.0f;
#pragma unroll 8
    for (int k = 0; k < IN_DIM; k++)
        acc += sx[rr][k] * W1[k * HID + d];
    int j = r0 + rr;
    float dc = 1.0f / sqrtf((float)(col_cnt[j] + 1));
    Y[(size_t)j * HID + d] = dc * acc;
}

// ---------------- kernel 4: fused SpMM layer 1 + W2 projection + dcol ----------------
__global__ __launch_bounds__(256) void spmm1_kernel(const float* __restrict__ Y,
                                                    const uint* __restrict__ bitmask,
                                                    const float* __restrict__ drow,
                                                    const int* __restrict__ col_cnt,
                                                    const float* __restrict__ W2,
                                                    float* __restrict__ Zc)
{
    int r = blockIdx.x * 4 + (threadIdx.x >> 6);
    r = __builtin_amdgcn_readfirstlane(r);       // wave-uniform -> SGPR
    int d = threadIdx.x & 63;
    const uint4* wp = (const uint4*)(bitmask + (size_t)r * 256);
    float acc0 = Y[(size_t)r * HID + d];         // identity (+I) term
    float acc1 = 0.0f;
    for (int q = 0; q < 64; q++) {
        uint4 wv = wp[q];                        // wave-uniform scalar load
        uint w0 = wv.x, w1 = wv.y, w2 = wv.z, w3 = wv.w;
        int cb = q * 128;
        while (w0) { int b = __ffs(w0) - 1; w0 &= w0 - 1; acc0 += Y[(size_t)(cb +      b) * HID + d]; }
        while (w1) { int b = __ffs(w1) - 1; w1 &= w1 - 1; acc1 += Y[(size_t)(cb + 32 + b) * HID + d]; }
        while (w2) { int b = __ffs(w2) - 1; w2 &= w2 - 1; acc0 += Y[(size_t)(cb + 64 + b) * HID + d]; }
        while (w3) { int b = __ffs(w3) - 1; w3 &= w3 - 1; acc1 += Y[(size_t)(cb + 96 + b) * HID + d]; }
    }
    float hv = drow[r] * (acc0 + acc1);
    float z0 = hv * W2[d * 2 + 0];
    float z1 = hv * W2[d * 2 + 1];
    for (int off = 32; off >= 1; off >>= 1) {
        z0 += __shfl_xor(z0, off, 64);
        z1 += __shfl_xor(z1, off, 64);
    }
    if (d == 0) {
        float dc = 1.0f / sqrtf((float)(col_cnt[r] + 1));
        Zc[r * 2 + 0] = dc * z0;
        Zc[r * 2 + 1] = dc * z1;
    }
}

// ---------------- kernel 5: SpMM layer 2 off the bitmask ----------------
__global__ __launch_bounds__(256) void spmm2_kernel(const float* __restrict__ Zc,
                                                    const uint* __restrict__ bitmask,
                                                    const float* __restrict__ drow,
                                                    float* __restrict__ out)
{
    int r = blockIdx.x * 4 + (threadIdx.x >> 6);
    r = __builtin_amdgcn_readfirstlane(r);
    int lane = threadIdx.x & 63;
    float a0 = 0.0f, a1 = 0.0f;
#pragma unroll
    for (int i = 0; i < 4; i++) {
        int wi = lane + i * 64;
        uint w = bitmask[(size_t)r * 256 + wi];
        int cb = wi * 32;
        while (w) {
            int b = __ffs(w) - 1;
            w &= w - 1;
            a0 += Zc[(cb + b) * 2 + 0];
            a1 += Zc[(cb + b) * 2 + 1];
        }
    }
    for (int off = 32; off >= 1; off >>= 1) {
        a0 += __shfl_xor(a0, off, 64);
        a1 += __shfl_xor(a1, off, 64);
    }
    if (lane == 0) {
        a0 += Zc[r * 2 + 0];                     // identity (+I) term
        a1 += Zc[r * 2 + 1];
        out[r * 2 + 0] = drow[r] * a0;
        out[r * 2 + 1] = drow[r] * a1;
    }
}

extern "C" void kernel_launch(void* const* d_in, const int* in_sizes, int n_in,
                              void* d_out, int out_size, void* d_ws, size_t ws_size,
                              hipStream_t stream)
{
    const float* x    = (const float*)d_in[0];
    // d_in[1] (adj) unused: adj.flat[idx] == 1.0 by construction
    const float* xdeg = (const float*)d_in[2];
    const float* ydeg = (const float*)d_in[3];
    const float* Wm1  = (const float*)d_in[4];
    const float* bm1  = (const float*)d_in[5];
    const float* Wm2  = (const float*)d_in[6];
    const float* bm2  = (const float*)d_in[7];
    const float* W1   = (const float*)d_in[8];
    const float* W2   = (const float*)d_in[9];
    const int*   idx  = (const int*)d_in[10];
    const int E = in_sizes[10];

    float* out = (float*)d_out;                       // [N*NC]
    float* adj_mask = out + (size_t)N * NC;           // [N*N]

    // ---- workspace carve ----
    char* ws = (char*)d_ws;
    size_t off = 0;
    auto carve = [&](size_t bytes) -> void* {
        void* p = ws + off;
        off += (bytes + 255) & ~(size_t)255;
        return p;
    };
    uint* bitmask = (uint*)carve(NWORDS * sizeof(uint));
    int* col_cnt  = (int*)carve((size_t)N * sizeof(int));   // adjacent to bitmask
    float* drow   = (float*)carve((size_t)N * sizeof(float));
    float* Y      = (float*)carve((size_t)N * HID * sizeof(float));
    float* Zc     = (float*)carve((size_t)N * NC * sizeof(float));

    // one memset covers bitmask + col_cnt (contiguous carve)
    hipMemsetAsync(bitmask, 0, NWORDS * sizeof(uint) + (size_t)N * sizeof(int), stream);

    dedup_or_kernel<<<(E + 255) / 256, 256, 0, stream>>>(idx, E, bitmask);
    mask_kernel<<<N, 512, 0, stream>>>(bitmask, xdeg, ydeg, Wm1, bm1, Wm2, bm2,
                                       adj_mask, drow, col_cnt);
    xw1_kernel<<<N / 4, 256, 0, stream>>>(x, W1, col_cnt, Y);
    spmm1_kernel<<<N / 4, 256, 0, stream>>>(Y, bitmask, drow, col_cnt, W2, Zc);
    spmm2_kernel<<<N / 4, 256, 0, stream>>>(Zc, bitmask, drow, out);
}